// Round 10
// baseline (165.269 us; speedup 1.0000x reference)
//
#include <hip/hip_runtime.h>
#include <hip/hip_bf16.h>
#include <hip/hip_fp16.h>

#define BS 8
#define C  256
#define N  9216
#define E  9215
#define MAXD 128               // off[] bins; actual depth <= 64 (6 doubling iters)
#define LVL_STRIDE 192         // per-batch ints: [0..128]=off, 129=maxd, 130=loE, 131=hiS
#define NARROW 64              // proven
#define NGT 31                 // weight tasks per batch: 8 tasks x 9ch + 23 x 8ch = 256
#define NBLK (BS + BS * NGT)   // 8 levels + 248 weights = 256 blocks = 256 CUs (1/CU)

typedef __attribute__((address_space(1))) const void GVoid;
typedef __attribute__((address_space(3))) void LVoid;

// ---------------------------------------------------------------------------
// Kernel 1: identical to R5/R7/R9 (proven; setup wall ~20 us).
// ---------------------------------------------------------------------------
__global__ __launch_bounds__(1024) void setup_kernel(const float* __restrict__ emb,
                                                     const int* __restrict__ tree,
                                                     float* __restrict__ distG,
                                                     int* __restrict__ uparr,
                                                     int* __restrict__ lvlOff) {
    __shared__ int P[N];
    __shared__ int U[N];
    __shared__ int cnt8[MAXD * 8];
    __shared__ int tot[MAXD];
    __shared__ int sc1[MAXD];
    __shared__ int off[MAXD + 1];
    __shared__ int maxd_sh;
    const int tid = threadIdx.x;

    if (blockIdx.x >= BS) {
        // ---- weights role ----
        const int wb = blockIdx.x - BS;        // [0,248)
        const int b  = wb & 7;
        const int g  = wb >> 3;                // [0,31)
        const int c0  = (g < 8) ? g * 9 : 72 + (g - 8) * 8;
        const int cpg = (g < 8) ? 9 : 8;
        const int wave = tid >> 6, lane = tid & 63;

        float* cur = (float*)P;
        float* nxt = (float*)U;

        int se[9];
        #pragma unroll
        for (int k = 0; k < 9; ++k) {
            int e = tid + k * 1024;
            se[k] = (e < E) ? tree[((size_t)b * E + e) * 2] : 0;
        }
        float acc[9];
        #pragma unroll
        for (int k = 0; k < 9; ++k) acc[k] = 0.f;

        const float* rowbase = emb + ((size_t)b * C + c0) * N;
        for (int chk = wave; chk < 36; chk += 16)
            __builtin_amdgcn_global_load_lds(
                (GVoid*)(rowbase + chk * 256 + lane * 4),
                (LVoid*)(cur + chk * 256), 16, 0, 0);
        __syncthreads();

        for (int cc = 0; cc < cpg; ++cc) {
            if (cc + 1 < cpg) {
                const float* src = rowbase + (size_t)(cc + 1) * N;
                for (int chk = wave; chk < 36; chk += 16)
                    __builtin_amdgcn_global_load_lds(
                        (GVoid*)(src + chk * 256 + lane * 4),
                        (LVoid*)(nxt + chk * 256), 16, 0, 0);
            }
            #pragma unroll
            for (int k = 0; k < 9; ++k) {
                int e = tid + k * 1024;
                if (e < E) {
                    float d = cur[se[k]] - cur[e + 1];   // tgt = e+1 (children=arange)
                    acc[k] += d * d;
                }
            }
            __syncthreads();
            float* t = cur; cur = nxt; nxt = t;
        }
        #pragma unroll
        for (int k = 0; k < 9; ++k) {
            int e = tid + k * 1024;
            if (e < E) atomicAdd(&distG[(size_t)b * N + e], acc[k]);
        }
        return;
    }

    // ---- levels role (unchanged, proven) ----
    const int b = blockIdx.x;
    const int* tb = tree + b * E * 2;

    for (int t = tid; t < N; t += 1024)
        P[t] = (t == 0) ? 0 : (tb[(t - 1) * 2] | (1 << 16));
    for (int i = tid; i < MAXD * 8; i += 1024) cnt8[i] = 0;
    if (tid == 0) maxd_sh = 1;
    __syncthreads();

    for (int r = 0; r < 3; ++r) {
        for (int t = tid; t < N; t += 1024) {
            int p = P[t];
            int a = p & 0xffff;
            if (a == 0) U[t] = p;
            else {
                int pa = P[a];
                U[t] = (pa & 0xffff) | (((p >> 16) + (pa >> 16)) << 16);
            }
        }
        __syncthreads();
        for (int t = tid; t < N; t += 1024) {
            int p = U[t];
            int a = p & 0xffff;
            if (a == 0) P[t] = p;
            else {
                int pa = U[a];
                P[t] = (pa & 0xffff) | (((p >> 16) + (pa >> 16)) << 16);
            }
        }
        __syncthreads();
    }

    for (int t = 1 + tid; t < N; t += 1024) {
        int d = P[t] >> 16;
        atomicAdd(&cnt8[d * 8 + (tid >> 7)], 1);
    }
    __syncthreads();

    for (int d = tid; d < MAXD; d += 1024) {
        int s = 0;
        #pragma unroll
        for (int k = 0; k < 8; ++k) {
            int v = cnt8[d * 8 + k];
            cnt8[d * 8 + k] = s;
            s += v;
        }
        tot[d] = s;
        if (s > 0) atomicMax(&maxd_sh, d);
    }
    __syncthreads();

    {
        int* src = tot; int* dst = sc1;
        for (int step = 1; step < MAXD; step <<= 1) {
            for (int d = tid; d < MAXD; d += 1024)
                dst[d] = src[d] + ((d >= step) ? src[d - step] : 0);
            __syncthreads();
            int* tmp = src; src = dst; dst = tmp;
        }
        for (int d = tid; d < MAXD; d += 1024) off[d + 1] = src[d];
        if (tid == 0) off[0] = 0;
    }
    __syncthreads();

    if (tid == 0) {
        int md = maxd_sh;
        int lo = 0;
        while (lo < md && off[lo + 2] - off[lo + 1] <= NARROW) ++lo;
        int hi = md + 1;
        while (hi > lo + 1 && off[hi] - off[hi - 1] <= NARROW) --hi;
        lvlOff[b * LVL_STRIDE + 129] = md;
        lvlOff[b * LVL_STRIDE + 130] = lo;
        lvlOff[b * LVL_STRIDE + 131] = hi;
    }
    for (int t = 1 + tid; t < N; t += 1024) {
        int d = P[t] >> 16;
        int idx = atomicAdd(&cnt8[d * 8 + (tid >> 7)], 1);
        int slot = off[d] + idx;
        int p = tb[(t - 1) * 2];
        U[slot] = t | (p << 16);
    }
    __syncthreads();

    for (int i = tid; i < E; i += 1024) uparr[b * N + i] = U[i];
    for (int i = tid; i <= MAXD; i += 1024) lvlOff[b * LVL_STRIDE + i] = off[i];
}

// ---------------------------------------------------------------------------
// Kernel 2 (R10): R9 init + up pass; DOWN PASS = affine pointer-doubling with
// STATIC k-slot register indexing (rule-#20 fix of R4's scratch spill).
// F[t] = a_t*F[p_t] + b_t, a=w, b=(1-w^2)*S[t]; root (0, 0, S[0]) fixed point.
// 6 Jacobi rounds (depth <= 64), read-all/barrier/write-all per round.
// (p,a) node-indexed in TSW; b node-indexed in V (write-through from regs).
// ---------------------------------------------------------------------------
__device__ __forceinline__ void up_edge(float2* V, const int2& ew) {
    int t = ew.x & 0xffff, p = ew.x >> 16;
    float w = __int_as_float(ew.y);
    float2 vt = V[t];
    atomicAdd(&V[p].x, w * vt.x);
    atomicAdd(&V[p].y, w * vt.y);
}

__global__ __launch_bounds__(1024) void dp_kernel(const float* __restrict__ feat,
                                                  const int* __restrict__ lvlOff,
                                                  const int* __restrict__ uparr,
                                                  const float* __restrict__ distG,
                                                  float* __restrict__ out) {
    const int b = blockIdx.x;
    const int tid = threadIdx.x;
    __shared__ float2 V[N];           // scratch: dist stage; then (F,G)/S; then b
    __shared__ int2 TSW[N];           // edges (level order); then node (p,a)
    __shared__ int off[MAXD + 1];
    __shared__ int meta[3];           // maxd, loE, hiS

    for (int i = tid; i <= MAXD; i += 1024) off[i] = lvlOff[b * LVL_STRIDE + i];
    if (tid < 3) meta[tid] = lvlOff[b * LVL_STRIDE + 129 + tid];

    // stage dist coalesced into V-scratch (36 KB)
    float* dScr = (float*)V;
    const float* dG = distG + b * N;
    for (int i = tid; i < N; i += 1024) dScr[i] = dG[i];
    __syncthreads();

    // TSW fill: coalesced ts + LDS gather + exp
    const int* uA = uparr + b * N;
    for (int i = tid; i < E; i += 1024) {
        int ts = uA[i];
        float ds = dScr[(ts & 0xffff) - 1];
        TSW[i] = make_int2(ts, __float_as_int(__expf(-0.01f * ds)));
    }
    __syncthreads();

    // V init (overwrites scratch)
    for (int i = tid; i < N; i += 1024)
        V[i] = make_float2(feat[b * N + i], 1.0f);
    __syncthreads();
    const int maxd = meta[0], loE = meta[1], hiS = meta[2];

    // ---- up pass (level-walk, R9 schedule) ----
    if (tid < 64) {                                  // narrow deep tail: wave 0
        for (int lev = maxd; lev >= hiS; --lev) {
            int s0 = off[lev], s1 = off[lev + 1];
            for (int i = s0 + tid; i < s1; i += 64) up_edge(V, TSW[i]);
            __threadfence_block();
        }
    }
    __syncthreads();
    for (int lev = hiS - 1; lev > loE; --lev) {      // wide middle: all 16 waves
        int s0 = off[lev], s1 = off[lev + 1];
        for (int i = s0 + tid; i < s1; i += 1024) up_edge(V, TSW[i]);
        __syncthreads();
    }
    if (tid < 64) {                                  // narrow top: wave 0
        for (int lev = loE; lev >= 1; --lev) {
            int s0 = off[lev], s1 = off[lev + 1];
            for (int i = s0 + tid; i < s1; i += 64) up_edge(V, TSW[i]);
            __threadfence_block();
        }
    }
    __syncthreads();                                 // V = S (post-up)

    // ---- down pass: affine pointer-doubling, static k-slots ----
    int   own_t[9], own_p[9];
    float own_a[9];
    float2 own_b[9];

    // Phase A read: edge list -> regs (slot k is compile-time)
    #pragma unroll
    for (int k = 0; k < 9; ++k) {
        int e = tid + k * 1024;
        if (e < E) {
            int2 ew = TSW[e];
            own_t[k] = ew.x & 0xffff;
            own_p[k] = ew.x >> 16;
            own_a[k] = __int_as_float(ew.y);
        } else { own_t[k] = 0; own_p[k] = 0; own_a[k] = 0.f; }
    }
    __syncthreads();                                 // all edge reads done

    // Phase A write: node-indexed (p,a) -> TSW[t]; b=(1-w^2)*S[t] -> V[t]+regs
    #pragma unroll
    for (int k = 0; k < 9; ++k) {
        int e = tid + k * 1024;
        if (e < E) {
            int t = own_t[k];
            float w = own_a[k], c = 1.f - w * w;
            float2 s = V[t];
            float2 bb = make_float2(c * s.x, c * s.y);
            own_b[k] = bb;
            V[t] = bb;
            TSW[t] = make_int2(own_p[k], __float_as_int(w));
        }
    }
    if (tid == 0) TSW[0] = make_int2(0, 0);          // root: p=0, a=0.0f
    __syncthreads();

    for (int r = 0; r < 6; ++r) {                    // 2^6 = 64 >= depth
        int   pp[9];
        float pa[9];
        float2 pb[9];
        #pragma unroll
        for (int k = 0; k < 9; ++k) {                // read parents (state r)
            int e = tid + k * 1024;
            if (e < E) {
                int p = own_p[k];
                int2 d = TSW[p];
                pp[k] = d.x;
                pa[k] = __int_as_float(d.y);
                pb[k] = V[p];
            } else { pp[k] = 0; pa[k] = 0.f; pb[k] = make_float2(0.f, 0.f); }
        }
        __syncthreads();
        #pragma unroll
        for (int k = 0; k < 9; ++k) {                // compose + publish r+1
            int e = tid + k * 1024;
            if (e < E) {
                float a = own_a[k];
                own_b[k].x = a * pb[k].x + own_b[k].x;
                own_b[k].y = a * pb[k].y + own_b[k].y;
                own_a[k] = a * pa[k];
                own_p[k] = pp[k];
                int t = own_t[k];
                V[t] = own_b[k];
                TSW[t] = make_int2(own_p[k], __float_as_int(own_a[k]));
            }
        }
        __syncthreads();
    }
    // V[t] = final (F,G); V[0] = S[0] untouched (correct for root)

    for (int i = tid; i < N; i += 1024) {
        float2 v = V[i];
        out[b * N + i] = v.x / v.y;
    }
}

extern "C" void kernel_launch(void* const* d_in, const int* in_sizes, int n_in,
                              void* d_out, int out_size, void* d_ws, size_t ws_size,
                              hipStream_t stream) {
    const float* feat = (const float*)d_in[0];   // [8,1,96,96]
    const float* emb  = (const float*)d_in[1];   // [8,256,96,96]
    const int*   tree = (const int*)d_in[2];     // [8,9215,2]
    float* out = (float*)d_out;                  // [8,1,96,96]

    const size_t BN = (size_t)BS * N;
    float* distG  = (float*)d_ws;                            // BN f32 (edge-indexed sq-dist)
    int*   uparr  = (int*)((char*)d_ws + BN * 4);            // BN i32 (level order)
    int*   lvlOff = (int*)((char*)d_ws + BN * 8);            // BS*LVL_STRIDE i32

    hipMemsetAsync(distG, 0, BN * sizeof(float), stream);    // capture-legal
    setup_kernel<<<NBLK, 1024, 0, stream>>>(emb, tree, distG, uparr, lvlOff);
    dp_kernel<<<BS, 1024, 0, stream>>>(feat, lvlOff, uparr, distG, out);
}

// Round 11
// 155.801 us; speedup vs baseline: 1.0608x; 1.0608x over previous
//
#include <hip/hip_runtime.h>
#include <hip/hip_bf16.h>
#include <hip/hip_fp16.h>

#define BS 8
#define C  256
#define N  9216
#define E  9215
#define MAXD 128               // off[] bins; actual depth <= 64 (6 doubling iters)
#define LVL_STRIDE 192         // per-batch ints: [0..128]=off, 129=maxd, 130=loE, 131=hiS
#define NARROW 64              // proven
#define NGT 31                 // weight tasks per batch: 8 tasks x 9ch + 23 x 8ch = 256
#define NBLK (BS + BS * NGT)   // 8 levels + 248 weights = 256 blocks = 256 CUs (1/CU)

typedef __attribute__((address_space(1))) const void GVoid;
typedef __attribute__((address_space(3))) void LVoid;

// ---------------------------------------------------------------------------
// Kernel 1: identical to R5/R7/R9 (proven; setup wall ~18-20 us).
// ---------------------------------------------------------------------------
__global__ __launch_bounds__(1024) void setup_kernel(const float* __restrict__ emb,
                                                     const int* __restrict__ tree,
                                                     float* __restrict__ distG,
                                                     int* __restrict__ uparr,
                                                     int* __restrict__ lvlOff) {
    __shared__ int P[N];
    __shared__ int U[N];
    __shared__ int cnt8[MAXD * 8];
    __shared__ int tot[MAXD];
    __shared__ int sc1[MAXD];
    __shared__ int off[MAXD + 1];
    __shared__ int maxd_sh;
    const int tid = threadIdx.x;

    if (blockIdx.x >= BS) {
        // ---- weights role ----
        const int wb = blockIdx.x - BS;        // [0,248)
        const int b  = wb & 7;
        const int g  = wb >> 3;                // [0,31)
        const int c0  = (g < 8) ? g * 9 : 72 + (g - 8) * 8;
        const int cpg = (g < 8) ? 9 : 8;
        const int wave = tid >> 6, lane = tid & 63;

        float* cur = (float*)P;
        float* nxt = (float*)U;

        int se[9];
        #pragma unroll
        for (int k = 0; k < 9; ++k) {
            int e = tid + k * 1024;
            se[k] = (e < E) ? tree[((size_t)b * E + e) * 2] : 0;
        }
        float acc[9];
        #pragma unroll
        for (int k = 0; k < 9; ++k) acc[k] = 0.f;

        const float* rowbase = emb + ((size_t)b * C + c0) * N;
        for (int chk = wave; chk < 36; chk += 16)
            __builtin_amdgcn_global_load_lds(
                (GVoid*)(rowbase + chk * 256 + lane * 4),
                (LVoid*)(cur + chk * 256), 16, 0, 0);
        __syncthreads();

        for (int cc = 0; cc < cpg; ++cc) {
            if (cc + 1 < cpg) {
                const float* src = rowbase + (size_t)(cc + 1) * N;
                for (int chk = wave; chk < 36; chk += 16)
                    __builtin_amdgcn_global_load_lds(
                        (GVoid*)(src + chk * 256 + lane * 4),
                        (LVoid*)(nxt + chk * 256), 16, 0, 0);
            }
            #pragma unroll
            for (int k = 0; k < 9; ++k) {
                int e = tid + k * 1024;
                if (e < E) {
                    float d = cur[se[k]] - cur[e + 1];   // tgt = e+1 (children=arange)
                    acc[k] += d * d;
                }
            }
            __syncthreads();
            float* t = cur; cur = nxt; nxt = t;
        }
        #pragma unroll
        for (int k = 0; k < 9; ++k) {
            int e = tid + k * 1024;
            if (e < E) atomicAdd(&distG[(size_t)b * N + e], acc[k]);
        }
        return;
    }

    // ---- levels role (unchanged, proven) ----
    const int b = blockIdx.x;
    const int* tb = tree + b * E * 2;

    for (int t = tid; t < N; t += 1024)
        P[t] = (t == 0) ? 0 : (tb[(t - 1) * 2] | (1 << 16));
    for (int i = tid; i < MAXD * 8; i += 1024) cnt8[i] = 0;
    if (tid == 0) maxd_sh = 1;
    __syncthreads();

    for (int r = 0; r < 3; ++r) {
        for (int t = tid; t < N; t += 1024) {
            int p = P[t];
            int a = p & 0xffff;
            if (a == 0) U[t] = p;
            else {
                int pa = P[a];
                U[t] = (pa & 0xffff) | (((p >> 16) + (pa >> 16)) << 16);
            }
        }
        __syncthreads();
        for (int t = tid; t < N; t += 1024) {
            int p = U[t];
            int a = p & 0xffff;
            if (a == 0) P[t] = p;
            else {
                int pa = U[a];
                P[t] = (pa & 0xffff) | (((p >> 16) + (pa >> 16)) << 16);
            }
        }
        __syncthreads();
    }

    for (int t = 1 + tid; t < N; t += 1024) {
        int d = P[t] >> 16;
        atomicAdd(&cnt8[d * 8 + (tid >> 7)], 1);
    }
    __syncthreads();

    for (int d = tid; d < MAXD; d += 1024) {
        int s = 0;
        #pragma unroll
        for (int k = 0; k < 8; ++k) {
            int v = cnt8[d * 8 + k];
            cnt8[d * 8 + k] = s;
            s += v;
        }
        tot[d] = s;
        if (s > 0) atomicMax(&maxd_sh, d);
    }
    __syncthreads();

    {
        int* src = tot; int* dst = sc1;
        for (int step = 1; step < MAXD; step <<= 1) {
            for (int d = tid; d < MAXD; d += 1024)
                dst[d] = src[d] + ((d >= step) ? src[d - step] : 0);
            __syncthreads();
            int* tmp = src; src = dst; dst = tmp;
        }
        for (int d = tid; d < MAXD; d += 1024) off[d + 1] = src[d];
        if (tid == 0) off[0] = 0;
    }
    __syncthreads();

    if (tid == 0) {
        int md = maxd_sh;
        int lo = 0;
        while (lo < md && off[lo + 2] - off[lo + 1] <= NARROW) ++lo;
        int hi = md + 1;
        while (hi > lo + 1 && off[hi] - off[hi - 1] <= NARROW) --hi;
        lvlOff[b * LVL_STRIDE + 129] = md;
        lvlOff[b * LVL_STRIDE + 130] = lo;
        lvlOff[b * LVL_STRIDE + 131] = hi;
    }
    for (int t = 1 + tid; t < N; t += 1024) {
        int d = P[t] >> 16;
        int idx = atomicAdd(&cnt8[d * 8 + (tid >> 7)], 1);
        int slot = off[d] + idx;
        int p = tb[(t - 1) * 2];
        U[slot] = t | (p << 16);
    }
    __syncthreads();

    for (int i = tid; i < E; i += 1024) uparr[b * N + i] = U[i];
    for (int i = tid; i <= MAXD; i += 1024) lvlOff[b * LVL_STRIDE + i] = off[i];
}

// ---------------------------------------------------------------------------
// Kernel 2 (R11): R9's proven walk + narrow-section software pipelining:
// next level's TSW edge (and, in down, the safe V[t']) is loaded BEFORE the
// fence so its ~120cy LDS latency hides under the fence's lgkmcnt(0) wait.
// Up's V[t] is NOT prefetched (written by preceding level's atomics).
// Init: dist staged via global_load_lds (setup's proven pattern).
// ---------------------------------------------------------------------------
__device__ __forceinline__ void up_edge(float2* V, const int2& ew) {
    int t = ew.x & 0xffff, p = ew.x >> 16;
    float w = __int_as_float(ew.y);
    float2 vt = V[t];
    atomicAdd(&V[p].x, w * vt.x);
    atomicAdd(&V[p].y, w * vt.y);
}

__device__ __forceinline__ void down_edge(float2* V, const int2& ew) {
    int t = ew.x & 0xffff, s = ew.x >> 16;
    float w = __int_as_float(ew.y);
    float2 vs = V[s], vt = V[t];
    float c = 1.f - w * w;
    V[t] = make_float2(w * vs.x + c * vt.x, w * vs.y + c * vt.y);
}

__global__ __launch_bounds__(1024) void dp_kernel(const float* __restrict__ feat,
                                                  const int* __restrict__ lvlOff,
                                                  const int* __restrict__ uparr,
                                                  const float* __restrict__ distG,
                                                  float* __restrict__ out) {
    const int b = blockIdx.x;
    const int tid = threadIdx.x;
    __shared__ float2 V[N];           // scratch: dist stage; then (F, G)
    __shared__ int2 TSW[N];           // (child|parent<<16, w bits), level order
    __shared__ int off[MAXD + 1];
    __shared__ int meta[3];           // maxd, loE, hiS

    for (int i = tid; i <= MAXD; i += 1024) off[i] = lvlOff[b * LVL_STRIDE + i];
    if (tid < 3) meta[tid] = lvlOff[b * LVL_STRIDE + 129 + tid];

    // stage dist into V-scratch via async global->LDS (36 KB = 36 x 1 KB chunks)
    float* dScr = (float*)V;
    {
        const int wave = tid >> 6, lane = tid & 63;
        const float* dG = distG + b * N;
        for (int chk = wave; chk < 36; chk += 16)
            __builtin_amdgcn_global_load_lds(
                (GVoid*)(dG + chk * 256 + lane * 4),
                (LVoid*)(dScr + chk * 256), 16, 0, 0);
    }
    __syncthreads();

    // TSW fill: coalesced ts + LDS gather + exp
    const int* uA = uparr + b * N;
    for (int i = tid; i < E; i += 1024) {
        int ts = uA[i];
        float ds = dScr[(ts & 0xffff) - 1];
        TSW[i] = make_int2(ts, __float_as_int(__expf(-0.01f * ds)));
    }
    __syncthreads();

    // V init (overwrites scratch)
    for (int i = tid; i < N; i += 1024)
        V[i] = make_float2(feat[b * N + i], 1.0f);
    __syncthreads();
    const int maxd = meta[0], loE = meta[1], hiS = meta[2];

    // ---- up pass (deepest level first) ----
    if (tid < 64) {                                  // narrow deep tail: pipelined
        int lev = maxd;
        int2 ew; bool val = false;
        if (lev >= hiS) {
            int s0 = off[lev], c = off[lev + 1] - s0;
            val = (tid < c); if (val) ew = TSW[s0 + tid];
        }
        for (; lev >= hiS; --lev) {
            int nl = lev - 1;
            int2 ewn; bool vn = false;
            if (nl >= hiS) {                         // prefetch next level's edge
                int s0 = off[nl], c = off[nl + 1] - s0;
                vn = (tid < c); if (vn) ewn = TSW[s0 + tid];
            }
            if (val) up_edge(V, ew);
            __threadfence_block();
            ew = ewn; val = vn;
        }
    }
    __syncthreads();
    for (int lev = hiS - 1; lev > loE; --lev) {      // wide middle: all 16 waves
        int s0 = off[lev], s1 = off[lev + 1];
        for (int i = s0 + tid; i < s1; i += 1024) up_edge(V, TSW[i]);
        __syncthreads();
    }
    if (tid < 64) {                                  // narrow top: pipelined
        int lev = loE;
        int2 ew; bool val = false;
        if (lev >= 1) {
            int s0 = off[lev], c = off[lev + 1] - s0;
            val = (tid < c); if (val) ew = TSW[s0 + tid];
        }
        for (; lev >= 1; --lev) {
            int nl = lev - 1;
            int2 ewn; bool vn = false;
            if (nl >= 1) {
                int s0 = off[nl], c = off[nl + 1] - s0;
                vn = (tid < c); if (vn) ewn = TSW[s0 + tid];
            }
            if (val) up_edge(V, ew);
            __threadfence_block();
            ew = ewn; val = vn;
        }
    }
    __syncthreads();

    // ---- down pass (root to leaf) ----
    if (tid < 64) {                                  // narrow top: pipelined
        int lev = 1;
        int2 ew; float2 vt; bool val = false;
        if (lev <= loE) {
            int s0 = off[lev], c = off[lev + 1] - s0;
            val = (tid < c);
            if (val) { ew = TSW[s0 + tid]; vt = V[ew.x & 0xffff]; }
        }
        for (; lev <= loE; ++lev) {
            int nl = lev + 1;
            int2 ewn; float2 vtn; bool vn = false;
            if (nl <= loE) {                         // prefetch edge + own V[t']
                int s0 = off[nl], c = off[nl + 1] - s0;
                vn = (tid < c);
                if (vn) { ewn = TSW[s0 + tid]; vtn = V[ewn.x & 0xffff]; }
            }
            if (val) {
                int t = ew.x & 0xffff, s = ew.x >> 16;
                float w = __int_as_float(ew.y);
                float2 vs = V[s];                    // chain-dependent load only
                float cc = 1.f - w * w;
                V[t] = make_float2(w * vs.x + cc * vt.x, w * vs.y + cc * vt.y);
            }
            __threadfence_block();
            ew = ewn; vt = vtn; val = vn;
        }
    }
    __syncthreads();
    for (int lev = loE + 1; lev < hiS; ++lev) {      // wide middle: all 16 waves
        int s0 = off[lev], s1 = off[lev + 1];
        for (int i = s0 + tid; i < s1; i += 1024) down_edge(V, TSW[i]);
        __syncthreads();
    }
    if (tid < 64) {                                  // narrow deep tail: pipelined
        int lev = hiS;
        int2 ew; float2 vt; bool val = false;
        if (lev <= maxd) {
            int s0 = off[lev], c = off[lev + 1] - s0;
            val = (tid < c);
            if (val) { ew = TSW[s0 + tid]; vt = V[ew.x & 0xffff]; }
        }
        for (; lev <= maxd; ++lev) {
            int nl = lev + 1;
            int2 ewn; float2 vtn; bool vn = false;
            if (nl <= maxd) {
                int s0 = off[nl], c = off[nl + 1] - s0;
                vn = (tid < c);
                if (vn) { ewn = TSW[s0 + tid]; vtn = V[ewn.x & 0xffff]; }
            }
            if (val) {
                int t = ew.x & 0xffff, s = ew.x >> 16;
                float w = __int_as_float(ew.y);
                float2 vs = V[s];
                float cc = 1.f - w * w;
                V[t] = make_float2(w * vs.x + cc * vt.x, w * vs.y + cc * vt.y);
            }
            __threadfence_block();
            ew = ewn; vt = vtn; val = vn;
        }
    }
    __syncthreads();

    for (int i = tid; i < N; i += 1024) {
        float2 v = V[i];
        out[b * N + i] = v.x / v.y;
    }
}

extern "C" void kernel_launch(void* const* d_in, const int* in_sizes, int n_in,
                              void* d_out, int out_size, void* d_ws, size_t ws_size,
                              hipStream_t stream) {
    const float* feat = (const float*)d_in[0];   // [8,1,96,96]
    const float* emb  = (const float*)d_in[1];   // [8,256,96,96]
    const int*   tree = (const int*)d_in[2];     // [8,9215,2]
    float* out = (float*)d_out;                  // [8,1,96,96]

    const size_t BN = (size_t)BS * N;
    float* distG  = (float*)d_ws;                            // BN f32 (edge-indexed sq-dist)
    int*   uparr  = (int*)((char*)d_ws + BN * 4);            // BN i32 (level order)
    int*   lvlOff = (int*)((char*)d_ws + BN * 8);            // BS*LVL_STRIDE i32

    hipMemsetAsync(distG, 0, BN * sizeof(float), stream);    // capture-legal
    setup_kernel<<<NBLK, 1024, 0, stream>>>(emb, tree, distG, uparr, lvlOff);
    dp_kernel<<<BS, 1024, 0, stream>>>(feat, lvlOff, uparr, distG, out);
}

// Round 12
// 152.185 us; speedup vs baseline: 1.0860x; 1.0238x over previous
//
#include <hip/hip_runtime.h>
#include <hip/hip_bf16.h>
#include <hip/hip_fp16.h>

#define BS 8
#define C  256
#define N  9216
#define E  9215
#define MAXD 128               // off[] bins; actual depth <= 64 (6 doubling iters)
#define LVL_STRIDE 192         // per-batch ints: [0..128]=off, 129=maxd, 130=loE, 131=hiS
#define NARROW 64              // proven
#define NGT 31                 // weight tasks per batch: 8 tasks x 9ch + 23 x 8ch = 256
#define NBLK (BS + BS * NGT)   // 8 levels + 248 weights = 256 blocks = 256 CUs (1/CU)

typedef __attribute__((address_space(1))) const void GVoid;
typedef __attribute__((address_space(3))) void LVoid;

// ---------------------------------------------------------------------------
// Kernel 1: identical to R5/R7/R9/R11 (proven; setup wall ~20 us, ~1.4x of
// its HBM floor: 9 channel-steps x 1.4us BW-bound + prologue/epilogue).
// ---------------------------------------------------------------------------
__global__ __launch_bounds__(1024) void setup_kernel(const float* __restrict__ emb,
                                                     const int* __restrict__ tree,
                                                     float* __restrict__ distG,
                                                     int* __restrict__ uparr,
                                                     int* __restrict__ lvlOff) {
    __shared__ int P[N];
    __shared__ int U[N];
    __shared__ int cnt8[MAXD * 8];
    __shared__ int tot[MAXD];
    __shared__ int sc1[MAXD];
    __shared__ int off[MAXD + 1];
    __shared__ int maxd_sh;
    const int tid = threadIdx.x;

    if (blockIdx.x >= BS) {
        // ---- weights role ----
        const int wb = blockIdx.x - BS;        // [0,248)
        const int b  = wb & 7;
        const int g  = wb >> 3;                // [0,31)
        const int c0  = (g < 8) ? g * 9 : 72 + (g - 8) * 8;
        const int cpg = (g < 8) ? 9 : 8;
        const int wave = tid >> 6, lane = tid & 63;

        float* cur = (float*)P;
        float* nxt = (float*)U;

        int se[9];
        #pragma unroll
        for (int k = 0; k < 9; ++k) {
            int e = tid + k * 1024;
            se[k] = (e < E) ? tree[((size_t)b * E + e) * 2] : 0;
        }
        float acc[9];
        #pragma unroll
        for (int k = 0; k < 9; ++k) acc[k] = 0.f;

        const float* rowbase = emb + ((size_t)b * C + c0) * N;
        for (int chk = wave; chk < 36; chk += 16)
            __builtin_amdgcn_global_load_lds(
                (GVoid*)(rowbase + chk * 256 + lane * 4),
                (LVoid*)(cur + chk * 256), 16, 0, 0);
        __syncthreads();

        for (int cc = 0; cc < cpg; ++cc) {
            if (cc + 1 < cpg) {
                const float* src = rowbase + (size_t)(cc + 1) * N;
                for (int chk = wave; chk < 36; chk += 16)
                    __builtin_amdgcn_global_load_lds(
                        (GVoid*)(src + chk * 256 + lane * 4),
                        (LVoid*)(nxt + chk * 256), 16, 0, 0);
            }
            #pragma unroll
            for (int k = 0; k < 9; ++k) {
                int e = tid + k * 1024;
                if (e < E) {
                    float d = cur[se[k]] - cur[e + 1];   // tgt = e+1 (children=arange)
                    acc[k] += d * d;
                }
            }
            __syncthreads();
            float* t = cur; cur = nxt; nxt = t;
        }
        #pragma unroll
        for (int k = 0; k < 9; ++k) {
            int e = tid + k * 1024;
            if (e < E) atomicAdd(&distG[(size_t)b * N + e], acc[k]);
        }
        return;
    }

    // ---- levels role (unchanged, proven) ----
    const int b = blockIdx.x;
    const int* tb = tree + b * E * 2;

    for (int t = tid; t < N; t += 1024)
        P[t] = (t == 0) ? 0 : (tb[(t - 1) * 2] | (1 << 16));
    for (int i = tid; i < MAXD * 8; i += 1024) cnt8[i] = 0;
    if (tid == 0) maxd_sh = 1;
    __syncthreads();

    for (int r = 0; r < 3; ++r) {
        for (int t = tid; t < N; t += 1024) {
            int p = P[t];
            int a = p & 0xffff;
            if (a == 0) U[t] = p;
            else {
                int pa = P[a];
                U[t] = (pa & 0xffff) | (((p >> 16) + (pa >> 16)) << 16);
            }
        }
        __syncthreads();
        for (int t = tid; t < N; t += 1024) {
            int p = U[t];
            int a = p & 0xffff;
            if (a == 0) P[t] = p;
            else {
                int pa = U[a];
                P[t] = (pa & 0xffff) | (((p >> 16) + (pa >> 16)) << 16);
            }
        }
        __syncthreads();
    }

    for (int t = 1 + tid; t < N; t += 1024) {
        int d = P[t] >> 16;
        atomicAdd(&cnt8[d * 8 + (tid >> 7)], 1);
    }
    __syncthreads();

    for (int d = tid; d < MAXD; d += 1024) {
        int s = 0;
        #pragma unroll
        for (int k = 0; k < 8; ++k) {
            int v = cnt8[d * 8 + k];
            cnt8[d * 8 + k] = s;
            s += v;
        }
        tot[d] = s;
        if (s > 0) atomicMax(&maxd_sh, d);
    }
    __syncthreads();

    {
        int* src = tot; int* dst = sc1;
        for (int step = 1; step < MAXD; step <<= 1) {
            for (int d = tid; d < MAXD; d += 1024)
                dst[d] = src[d] + ((d >= step) ? src[d - step] : 0);
            __syncthreads();
            int* tmp = src; src = dst; dst = tmp;
        }
        for (int d = tid; d < MAXD; d += 1024) off[d + 1] = src[d];
        if (tid == 0) off[0] = 0;
    }
    __syncthreads();

    if (tid == 0) {
        int md = maxd_sh;
        int lo = 0;
        while (lo < md && off[lo + 2] - off[lo + 1] <= NARROW) ++lo;
        int hi = md + 1;
        while (hi > lo + 1 && off[hi] - off[hi - 1] <= NARROW) --hi;
        lvlOff[b * LVL_STRIDE + 129] = md;
        lvlOff[b * LVL_STRIDE + 130] = lo;
        lvlOff[b * LVL_STRIDE + 131] = hi;
    }
    for (int t = 1 + tid; t < N; t += 1024) {
        int d = P[t] >> 16;
        int idx = atomicAdd(&cnt8[d * 8 + (tid >> 7)], 1);
        int slot = off[d] + idx;
        int p = tb[(t - 1) * 2];
        U[slot] = t | (p << 16);
    }
    __syncthreads();

    for (int i = tid; i < E; i += 1024) uparr[b * N + i] = U[i];
    for (int i = tid; i <= MAXD; i += 1024) lvlOff[b * LVL_STRIDE + i] = off[i];
}

// ---------------------------------------------------------------------------
// Kernel 2 (R12): single-shot init overlap. dist scratch lives in TSW space
// (dead until the fill), so dist gload_lds + uparr->regs + feat->regs + off/
// meta ALL issue before barrier 1 (one latency shadow for ~110 KB of global
// traffic). Phase 1: exp-gather into regs + V init. Phase 2: TSW write from
// regs (overwrites scratch, after barrier). Walk = R11's proven pipelined
// schedule, unchanged. All per-thread arrays statically indexed (rule #20).
// ---------------------------------------------------------------------------
__device__ __forceinline__ void up_edge(float2* V, const int2& ew) {
    int t = ew.x & 0xffff, p = ew.x >> 16;
    float w = __int_as_float(ew.y);
    float2 vt = V[t];
    atomicAdd(&V[p].x, w * vt.x);
    atomicAdd(&V[p].y, w * vt.y);
}

__device__ __forceinline__ void down_edge(float2* V, const int2& ew) {
    int t = ew.x & 0xffff, s = ew.x >> 16;
    float w = __int_as_float(ew.y);
    float2 vs = V[s], vt = V[t];
    float c = 1.f - w * w;
    V[t] = make_float2(w * vs.x + c * vt.x, w * vs.y + c * vt.y);
}

__global__ __launch_bounds__(1024) void dp_kernel(const float* __restrict__ feat,
                                                  const int* __restrict__ lvlOff,
                                                  const int* __restrict__ uparr,
                                                  const float* __restrict__ distG,
                                                  float* __restrict__ out) {
    const int b = blockIdx.x;
    const int tid = threadIdx.x;
    __shared__ float2 V[N];           // (F, G)
    __shared__ int2 TSW[N];           // scratch: dist stage (first 36 KB); then edges
    __shared__ int off[MAXD + 1];
    __shared__ int meta[3];           // maxd, loE, hiS

    // ---- phase 0: issue ALL independent global traffic, then one barrier ----
    float* dScr = (float*)TSW;        // 36 KB dist scratch in TSW space
    {
        const int wave = tid >> 6, lane = tid & 63;
        const float* dG = distG + b * N;
        for (int chk = wave; chk < 36; chk += 16)
            __builtin_amdgcn_global_load_lds(
                (GVoid*)(dG + chk * 256 + lane * 4),
                (LVoid*)(dScr + chk * 256), 16, 0, 0);
    }
    int ts[9];
    const int* uA = uparr + b * N;
    #pragma unroll
    for (int k = 0; k < 9; ++k) {
        int e = tid + k * 1024;
        ts[k] = (e < E) ? uA[e] : 0;
    }
    float ft[9];
    const float* fB = feat + b * N;
    #pragma unroll
    for (int k = 0; k < 9; ++k)
        ft[k] = fB[tid + k * 1024];                  // N = 9*1024, all valid
    for (int i = tid; i <= MAXD; i += 1024) off[i] = lvlOff[b * LVL_STRIDE + i];
    if (tid < 3) meta[tid] = lvlOff[b * LVL_STRIDE + 129 + tid];
    __syncthreads();                                 // dist in dScr; regs ready

    // ---- phase 1: exp-gather into regs; V init (V untouched by staging) ----
    float wv[9];
    #pragma unroll
    for (int k = 0; k < 9; ++k) {
        int e = tid + k * 1024;
        wv[k] = (e < E) ? __expf(-0.01f * dScr[(ts[k] & 0xffff) - 1]) : 0.f;
    }
    #pragma unroll
    for (int k = 0; k < 9; ++k)
        V[tid + k * 1024] = make_float2(ft[k], 1.0f);
    __syncthreads();                                 // all dScr reads done

    // ---- phase 2: TSW write from regs (overwrites scratch safely) ----
    #pragma unroll
    for (int k = 0; k < 9; ++k) {
        int e = tid + k * 1024;
        if (e < E) TSW[e] = make_int2(ts[k], __float_as_int(wv[k]));
    }
    __syncthreads();
    const int maxd = meta[0], loE = meta[1], hiS = meta[2];

    // ---- up pass (deepest level first; R11 pipelined schedule) ----
    if (tid < 64) {                                  // narrow deep tail: pipelined
        int lev = maxd;
        int2 ew; bool val = false;
        if (lev >= hiS) {
            int s0 = off[lev], c = off[lev + 1] - s0;
            val = (tid < c); if (val) ew = TSW[s0 + tid];
        }
        for (; lev >= hiS; --lev) {
            int nl = lev - 1;
            int2 ewn; bool vn = false;
            if (nl >= hiS) {                         // prefetch next level's edge
                int s0 = off[nl], c = off[nl + 1] - s0;
                vn = (tid < c); if (vn) ewn = TSW[s0 + tid];
            }
            if (val) up_edge(V, ew);
            __threadfence_block();
            ew = ewn; val = vn;
        }
    }
    __syncthreads();
    for (int lev = hiS - 1; lev > loE; --lev) {      // wide middle: all 16 waves
        int s0 = off[lev], s1 = off[lev + 1];
        for (int i = s0 + tid; i < s1; i += 1024) up_edge(V, TSW[i]);
        __syncthreads();
    }
    if (tid < 64) {                                  // narrow top: pipelined
        int lev = loE;
        int2 ew; bool val = false;
        if (lev >= 1) {
            int s0 = off[lev], c = off[lev + 1] - s0;
            val = (tid < c); if (val) ew = TSW[s0 + tid];
        }
        for (; lev >= 1; --lev) {
            int nl = lev - 1;
            int2 ewn; bool vn = false;
            if (nl >= 1) {
                int s0 = off[nl], c = off[nl + 1] - s0;
                vn = (tid < c); if (vn) ewn = TSW[s0 + tid];
            }
            if (val) up_edge(V, ew);
            __threadfence_block();
            ew = ewn; val = vn;
        }
    }
    __syncthreads();

    // ---- down pass (root to leaf; R11 pipelined schedule) ----
    if (tid < 64) {                                  // narrow top: pipelined
        int lev = 1;
        int2 ew; float2 vt; bool val = false;
        if (lev <= loE) {
            int s0 = off[lev], c = off[lev + 1] - s0;
            val = (tid < c);
            if (val) { ew = TSW[s0 + tid]; vt = V[ew.x & 0xffff]; }
        }
        for (; lev <= loE; ++lev) {
            int nl = lev + 1;
            int2 ewn; float2 vtn; bool vn = false;
            if (nl <= loE) {                         // prefetch edge + own V[t']
                int s0 = off[nl], c = off[nl + 1] - s0;
                vn = (tid < c);
                if (vn) { ewn = TSW[s0 + tid]; vtn = V[ewn.x & 0xffff]; }
            }
            if (val) {
                int t = ew.x & 0xffff, s = ew.x >> 16;
                float w = __int_as_float(ew.y);
                float2 vs = V[s];                    // chain-dependent load only
                float cc = 1.f - w * w;
                V[t] = make_float2(w * vs.x + cc * vt.x, w * vs.y + cc * vt.y);
            }
            __threadfence_block();
            ew = ewn; vt = vtn; val = vn;
        }
    }
    __syncthreads();
    for (int lev = loE + 1; lev < hiS; ++lev) {      // wide middle: all 16 waves
        int s0 = off[lev], s1 = off[lev + 1];
        for (int i = s0 + tid; i < s1; i += 1024) down_edge(V, TSW[i]);
        __syncthreads();
    }
    if (tid < 64) {                                  // narrow deep tail: pipelined
        int lev = hiS;
        int2 ew; float2 vt; bool val = false;
        if (lev <= maxd) {
            int s0 = off[lev], c = off[lev + 1] - s0;
            val = (tid < c);
            if (val) { ew = TSW[s0 + tid]; vt = V[ew.x & 0xffff]; }
        }
        for (; lev <= maxd; ++lev) {
            int nl = lev + 1;
            int2 ewn; float2 vtn; bool vn = false;
            if (nl <= maxd) {
                int s0 = off[nl], c = off[nl + 1] - s0;
                vn = (tid < c);
                if (vn) { ewn = TSW[s0 + tid]; vtn = V[ewn.x & 0xffff]; }
            }
            if (val) {
                int t = ew.x & 0xffff, s = ew.x >> 16;
                float w = __int_as_float(ew.y);
                float2 vs = V[s];
                float cc = 1.f - w * w;
                V[t] = make_float2(w * vs.x + cc * vt.x, w * vs.y + cc * vt.y);
            }
            __threadfence_block();
            ew = ewn; vt = vtn; val = vn;
        }
    }
    __syncthreads();

    for (int i = tid; i < N; i += 1024) {
        float2 v = V[i];
        out[b * N + i] = v.x / v.y;
    }
}

extern "C" void kernel_launch(void* const* d_in, const int* in_sizes, int n_in,
                              void* d_out, int out_size, void* d_ws, size_t ws_size,
                              hipStream_t stream) {
    const float* feat = (const float*)d_in[0];   // [8,1,96,96]
    const float* emb  = (const float*)d_in[1];   // [8,256,96,96]
    const int*   tree = (const int*)d_in[2];     // [8,9215,2]
    float* out = (float*)d_out;                  // [8,1,96,96]

    const size_t BN = (size_t)BS * N;
    float* distG  = (float*)d_ws;                            // BN f32 (edge-indexed sq-dist)
    int*   uparr  = (int*)((char*)d_ws + BN * 4);            // BN i32 (level order)
    int*   lvlOff = (int*)((char*)d_ws + BN * 8);            // BS*LVL_STRIDE i32

    hipMemsetAsync(distG, 0, BN * sizeof(float), stream);    // capture-legal
    setup_kernel<<<NBLK, 1024, 0, stream>>>(emb, tree, distG, uparr, lvlOff);
    dp_kernel<<<BS, 1024, 0, stream>>>(feat, lvlOff, uparr, distG, out);
}